// Round 3
// baseline (790.973 us; speedup 1.0000x reference)
//
#include <hip/hip_runtime.h>
#include <hip/hip_bf16.h>
#include <math.h>

typedef __hip_bfloat16 bf16;
typedef short bf16x8 __attribute__((ext_vector_type(8)));   // 8 bf16 raw (4 VGPRs)
typedef float f32x4 __attribute__((ext_vector_type(4)));

union alignas(16) Pack8 { bf16 h[8]; bf16x8 v; };

// ---------------------------------------------------------------------------
// Weight transpose f32 -> bf16: out[n*K + k] = (bf16) in[k*N + n]
// ---------------------------------------------------------------------------
__global__ void transpose_w(const float* __restrict__ in, bf16* __restrict__ out,
                            int K, int N) {
    int idx = blockIdx.x * 256 + threadIdx.x;
    if (idx >= K * N) return;
    int n = idx / K;
    int k = idx - n * K;
    out[idx] = __float2bfloat16(in[k * N + n]);
}

// ---------------------------------------------------------------------------
// MLP layer GEMM: Y = relu(X @ W). X:[8192,KDIM] (f32 if F32IN else bf16),
// Wt:[256,KDIM] bf16 (pre-transposed), Y:[8192,256] bf16.
// Block = 64 rows x all 256 cols (4 waves, each 64x64 via 4x4 16x16x32 MFMA).
// A block reads all K of its 64 rows before writing those same 64 rows, and
// blocks touch disjoint rows -> layer 2 may run in-place (Y aliases X).
// ---------------------------------------------------------------------------
template<int KDIM, bool F32IN>
__global__ __launch_bounds__(256)
void mlp_gemm(const void* __restrict__ Xq, const void* __restrict__ Xk,
              const bf16* __restrict__ Wt,
              bf16* __restrict__ Yq, bf16* __restrict__ Yk) {
    const void* X = blockIdx.z ? Xk : Xq;
    bf16* Y = blockIdx.z ? Yk : Yq;
    const int m0 = blockIdx.x * 64;

    __shared__ short lA[64 * 40];    // 64 rows x 32 k (+8 pad)
    __shared__ short lB[256 * 40];   // 256 n-rows x 32 k (+8 pad)

    const int tid  = threadIdx.x;
    const int wave = tid >> 6, lane = tid & 63;
    const int wn = wave * 64;
    const int quad = lane >> 4, r16 = lane & 15;

    f32x4 acc[4][4] = {};

    for (int kk = 0; kk < KDIM; kk += 32) {
        // stage A tile: one (row, 8-col chunk) per thread
        {
            int r = tid >> 2;
            int c = (tid & 3) * 8;
            if (F32IN) {
                const float* p = (const float*)X + (size_t)(m0 + r) * KDIM + kk + c;
                Pack8 u;
#pragma unroll
                for (int j = 0; j < 8; j++) u.h[j] = __float2bfloat16(p[j]);
                *(bf16x8*)&lA[r * 40 + c] = u.v;
            } else {
                *(bf16x8*)&lA[r * 40 + c] =
                    *(const bf16x8*)((const bf16*)X + (size_t)(m0 + r) * KDIM + kk + c);
            }
        }
        // stage B tile (bf16): 256 n-rows x 32 k
        for (int i = tid; i < 1024; i += 256) {
            int r = i >> 2;
            int c = (i & 3) * 8;
            *(bf16x8*)&lB[r * 40 + c] =
                *(const bf16x8*)(Wt + (size_t)r * KDIM + kk + c);
        }
        __syncthreads();
        bf16x8 af[4], bfr[4];
#pragma unroll
        for (int f = 0; f < 4; f++) {
            af[f]  = *(const bf16x8*)&lA[(f * 16 + r16) * 40 + quad * 8];
            bfr[f] = *(const bf16x8*)&lB[(wn + f * 16 + r16) * 40 + quad * 8];
        }
#pragma unroll
        for (int i = 0; i < 4; i++)
#pragma unroll
            for (int j = 0; j < 4; j++)
                acc[i][j] = __builtin_amdgcn_mfma_f32_16x16x32_bf16(
                    af[i], bfr[j], acc[i][j], 0, 0, 0);
        __syncthreads();
    }

#pragma unroll
    for (int i = 0; i < 4; i++) {
        int rbase = m0 + i * 16 + quad * 4;
#pragma unroll
        for (int j = 0; j < 4; j++) {
            int col = wn + j * 16 + r16;
#pragma unroll
            for (int r = 0; r < 4; r++) {
                float v = acc[i][j][r];
                v = v > 0.f ? v : 0.f;
                Y[(size_t)(rbase + r) * 256 + col] = __float2bfloat16(v);
            }
        }
    }
}

// ---------------------------------------------------------------------------
// HardKuma elementwise (eval mode), f32 in registers
// ---------------------------------------------------------------------------
__device__ __forceinline__ float hardkuma(float la, float lb) {
    float a = la > 20.f ? la : log1pf(__expf(la));
    a = fminf(fmaxf(a, 0.01f), 100.f);
    float b = lb > 20.f ? lb : log1pf(__expf(lb));
    b = fminf(fmaxf(b, 0.01f), 100.f);

    const float lt0 = -2.4849066497880004f;   // ln(1/12)
    const float lt1 = -0.08701137698962981f;  // ln(11/12)

    float q0 = __expf(b * __logf(-expm1f(a * lt0)));   // (1 - t0^a)^b
    float p0 = 1.f - q0;                               // P(h=0)
    float p1 = __expf(b * __logf(-expm1f(a * lt1)));   // P(h=1)
    float pc = q0 - p1;                                // 1 - p0 - p1

    float g = 1.f + 1.f / a;
    float lbeta = lgammaf(g) + lgammaf(b) - lgammaf(g + b);
    float mean = -0.1f + 1.2f * (b * __expf(lbeta));
    mean = fminf(fmaxf(mean, 0.f), 1.f);

    float zo = (p0 > p1) ? 0.f : 1.f;
    return (pc < 0.5f) ? zo : mean;
}

// ---------------------------------------------------------------------------
// Fused score GEMMs + HardKuma epilogue. grid (T/128, T/128, B); f32 output.
// ---------------------------------------------------------------------------
__global__ __launch_bounds__(256)
void kuma_attn(const bf16* __restrict__ qa, const bf16* __restrict__ ka,
               const bf16* __restrict__ qb, const bf16* __restrict__ kb,
               const float* __restrict__ dist_emb, float* __restrict__ out) {
    const int bidx = blockIdx.z;
    const int t0 = blockIdx.x * 128;
    const int s0 = blockIdx.y * 128;

    __shared__ short lQa[128 * 40], lKa[128 * 40];
    __shared__ short lQb[128 * 40], lKb[128 * 40];
    __shared__ float sDist[23];

    const int tid = threadIdx.x;
    if (tid < 23) sDist[tid] = dist_emb[tid];

    const int wave = tid >> 6, lane = tid & 63;
    const int wm = (wave >> 1) * 64, wn = (wave & 1) * 64;
    const int quad = lane >> 4, r16 = lane & 15;
    const size_t base = (size_t)bidx * 2048 * 256;

    f32x4 accA[4][4] = {};
    f32x4 accB[4][4] = {};

    for (int kk = 0; kk < 256; kk += 32) {
        for (int i = tid; i < 512; i += 256) {
            int r = i >> 2;
            int c = (i & 3) * 8;
            size_t gq = base + (size_t)(t0 + r) * 256 + kk + c;
            size_t gk = base + (size_t)(s0 + r) * 256 + kk + c;
            *(bf16x8*)&lQa[r * 40 + c] = *(const bf16x8*)(qa + gq);
            *(bf16x8*)&lKa[r * 40 + c] = *(const bf16x8*)(ka + gk);
            *(bf16x8*)&lQb[r * 40 + c] = *(const bf16x8*)(qb + gq);
            *(bf16x8*)&lKb[r * 40 + c] = *(const bf16x8*)(kb + gk);
        }
        __syncthreads();
        bf16x8 aA[4], bA[4], aB[4], bB[4];
#pragma unroll
        for (int f = 0; f < 4; f++) {
            int ar = (wm + f * 16 + r16) * 40 + quad * 8;
            int br = (wn + f * 16 + r16) * 40 + quad * 8;
            aA[f] = *(const bf16x8*)&lQa[ar];
            bA[f] = *(const bf16x8*)&lKa[br];
            aB[f] = *(const bf16x8*)&lQb[ar];
            bB[f] = *(const bf16x8*)&lKb[br];
        }
#pragma unroll
        for (int i = 0; i < 4; i++)
#pragma unroll
            for (int j = 0; j < 4; j++) {
                accA[i][j] = __builtin_amdgcn_mfma_f32_16x16x32_bf16(
                    aA[i], bA[j], accA[i][j], 0, 0, 0);
                accB[i][j] = __builtin_amdgcn_mfma_f32_16x16x32_bf16(
                    aB[i], bB[j], accB[i][j], 0, 0, 0);
            }
        __syncthreads();
    }

#pragma unroll
    for (int i = 0; i < 4; i++) {
#pragma unroll
        for (int j = 0; j < 4; j++) {
            int s = s0 + wn + j * 16 + r16;
#pragma unroll
            for (int r = 0; r < 4; r++) {
                int t = t0 + wm + i * 16 + quad * 4 + r;
                int d = s - t;
                d = d < -11 ? -11 : (d > 11 ? 11 : d);
                float rd = sDist[d + 11];
                float att = hardkuma(accA[i][j][r] + rd, accB[i][j][r] + rd);
                out[((size_t)bidx * 2048 + t) * 2048 + s] = att;
            }
        }
    }
}

// ---------------------------------------------------------------------------
extern "C" void kernel_launch(void* const* d_in, const int* in_sizes, int n_in,
                              void* d_out, int out_size, void* d_ws, size_t ws_size,
                              hipStream_t stream) {
    const float* q    = (const float*)d_in[0];
    const float* k    = (const float*)d_in[1];
    const float* Wa1  = (const float*)d_in[2];
    const float* Wa2  = (const float*)d_in[4];
    const float* Wb1  = (const float*)d_in[6];
    const float* Wb2  = (const float*)d_in[8];
    const float* dist = (const float*)d_in[10];
    float* out = (float*)d_out;

    bf16* wsbf = (bf16*)d_ws;
    bf16* Wa1t = wsbf;                 // 512*256
    bf16* Wa2t = Wa1t + 131072;        // 256*256
    bf16* Wb1t = Wa2t + 65536;
    bf16* Wb2t = Wb1t + 131072;
    bf16* qa   = Wb2t + 65536;         // 8192*256 each
    bf16* ka   = qa + 2097152;
    bf16* qb   = ka + 2097152;
    bf16* kb   = qb + 2097152;
    // total ws: ~17.6 MB

    transpose_w<<<512, 256, 0, stream>>>(Wa1, Wa1t, 512, 256);
    transpose_w<<<256, 256, 0, stream>>>(Wa2, Wa2t, 256, 256);
    transpose_w<<<512, 256, 0, stream>>>(Wb1, Wb1t, 512, 256);
    transpose_w<<<256, 256, 0, stream>>>(Wb2, Wb2t, 256, 256);

    dim3 g1(128, 1, 2), blk(256, 1, 1);
    // branch a: layer 1 (q,k f32 -> qa,ka bf16), layer 2 in-place bf16
    mlp_gemm<512, true ><<<g1, blk, 0, stream>>>(q, k, Wa1t, qa, ka);
    mlp_gemm<256, false><<<g1, blk, 0, stream>>>(qa, ka, Wa2t, qa, ka);
    // branch b
    mlp_gemm<512, true ><<<g1, blk, 0, stream>>>(q, k, Wb1t, qb, kb);
    mlp_gemm<256, false><<<g1, blk, 0, stream>>>(qb, kb, Wb2t, qb, kb);

    dim3 g2(16, 16, 4);
    kuma_attn<<<g2, blk, 0, stream>>>(qa, ka, qb, kb, dist, out);
}

// Round 4
// 435.405 us; speedup vs baseline: 1.8166x; 1.8166x over previous
//
#include <hip/hip_runtime.h>
#include <hip/hip_bf16.h>
#include <math.h>

typedef __hip_bfloat16 bf16;
typedef short bf16x8 __attribute__((ext_vector_type(8)));   // 8 bf16 raw (4 VGPRs)
typedef float f32x4 __attribute__((ext_vector_type(4)));

union alignas(16) Pack8 { bf16 h[8]; bf16x8 v; };

// ---------------------------------------------------------------------------
// All four weight transposes f32 -> bf16 in one dispatch.
// outX[n*K + k] = (bf16) inX[k*N + n], N = 256 always.
// ---------------------------------------------------------------------------
__global__ void prep_weights(const float* __restrict__ Wa1, const float* __restrict__ Wa2,
                             const float* __restrict__ Wb1, const float* __restrict__ Wb2,
                             bf16* __restrict__ oa1, bf16* __restrict__ oa2,
                             bf16* __restrict__ ob1, bf16* __restrict__ ob2) {
    int idx = blockIdx.x * 256 + threadIdx.x;   // grid covers 393216
    if (idx < 131072) {
        int n = idx >> 9, k = idx & 511;
        oa1[idx] = __float2bfloat16(Wa1[k * 256 + n]);
    } else if (idx < 196608) {
        int i = idx - 131072; int n = i >> 8, k = i & 255;
        oa2[i] = __float2bfloat16(Wa2[k * 256 + n]);
    } else if (idx < 327680) {
        int i = idx - 196608; int n = i >> 9, k = i & 511;
        ob1[i] = __float2bfloat16(Wb1[k * 256 + n]);
    } else {
        int i = idx - 327680; int n = i >> 8, k = i & 255;
        ob2[i] = __float2bfloat16(Wb2[k * 256 + n]);
    }
}

// ---------------------------------------------------------------------------
// MLP layer GEMM: Y = relu(X @ W). X:[8192,KDIM] (f32 if F32IN else bf16),
// Wt:[256,KDIM] bf16, Y:[8192,256] bf16. Block = 64 rows x 256 cols.
// Blocks touch disjoint rows and read all K before writing -> in-place OK.
// ---------------------------------------------------------------------------
template<int KDIM, bool F32IN>
__global__ __launch_bounds__(256)
void mlp_gemm(const void* __restrict__ Xq, const void* __restrict__ Xk,
              const bf16* __restrict__ Wt,
              bf16* __restrict__ Yq, bf16* __restrict__ Yk) {
    const void* X = blockIdx.z ? Xk : Xq;
    bf16* Y = blockIdx.z ? Yk : Yq;
    const int m0 = blockIdx.x * 64;

    __shared__ short lA[64 * 40];
    __shared__ short lB[256 * 40];

    const int tid  = threadIdx.x;
    const int wave = tid >> 6, lane = tid & 63;
    const int wn = wave * 64;
    const int quad = lane >> 4, r16 = lane & 15;

    f32x4 acc[4][4] = {};

    for (int kk = 0; kk < KDIM; kk += 32) {
        {
            int r = tid >> 2;
            int c = (tid & 3) * 8;
            if (F32IN) {
                const float* p = (const float*)X + (size_t)(m0 + r) * KDIM + kk + c;
                Pack8 u;
#pragma unroll
                for (int j = 0; j < 8; j++) u.h[j] = __float2bfloat16(p[j]);
                *(bf16x8*)&lA[r * 40 + c] = u.v;
            } else {
                *(bf16x8*)&lA[r * 40 + c] =
                    *(const bf16x8*)((const bf16*)X + (size_t)(m0 + r) * KDIM + kk + c);
            }
        }
        for (int i = tid; i < 1024; i += 256) {
            int r = i >> 2;
            int c = (i & 3) * 8;
            *(bf16x8*)&lB[r * 40 + c] =
                *(const bf16x8*)(Wt + (size_t)r * KDIM + kk + c);
        }
        __syncthreads();
        bf16x8 af[4], bfr[4];
#pragma unroll
        for (int f = 0; f < 4; f++) {
            af[f]  = *(const bf16x8*)&lA[(f * 16 + r16) * 40 + quad * 8];
            bfr[f] = *(const bf16x8*)&lB[(wn + f * 16 + r16) * 40 + quad * 8];
        }
#pragma unroll
        for (int i = 0; i < 4; i++)
#pragma unroll
            for (int j = 0; j < 4; j++)
                acc[i][j] = __builtin_amdgcn_mfma_f32_16x16x32_bf16(
                    af[i], bfr[j], acc[i][j], 0, 0, 0);
        __syncthreads();
    }

#pragma unroll
    for (int i = 0; i < 4; i++) {
        int rbase = m0 + i * 16 + quad * 4;
#pragma unroll
        for (int j = 0; j < 4; j++) {
            int col = wn + j * 16 + r16;
#pragma unroll
            for (int r = 0; r < 4; r++) {
                float v = acc[i][j][r];
                v = v > 0.f ? v : 0.f;
                Y[(size_t)(rbase + r) * 256 + col] = __float2bfloat16(v);
            }
        }
    }
}

// ---------------------------------------------------------------------------
// Fast range-reduced math (replaces libm lgammaf / log1pf / expm1f)
// ---------------------------------------------------------------------------
__device__ __forceinline__ float softplus_f(float x) {
    float r = __logf(1.f + __expf(x));
    return x > 15.f ? x : r;
}

// expm1 for y <= 0; exact enough on [-inf, 0]
__device__ __forceinline__ float expm1_neg(float y) {
    float p = y * (1.f + y * (0.5f + y * (1.f/6.f + y * (1.f/24.f +
              y * (1.f/120.f + y * (1.f/720.f))))));
    float e = __expf(y) - 1.f;
    return y > -0.28f ? p : e;
}

// lgamma for x in [0.01, ~210]: shift into Stirling's domain via
// Gamma(x+8) = x(x+1)...(x+7) Gamma(x); Stirling w/ 2 correction terms.
__device__ __forceinline__ float fast_lgamma(float x) {
    float p = x * (x + 1.f) * (x + 2.f) * (x + 3.f)
                * (x + 4.f) * (x + 5.f) * (x + 6.f) * (x + 7.f);
    bool small = x < 8.f;
    float z  = small ? x + 8.f : x;
    float lz = __logf(z);
    float iz = __builtin_amdgcn_rcpf(z);
    float lg = (z - 0.5f) * lz - z + 0.918938533f
             + iz * (0.0833333333f - 0.0027777778f * iz * iz);
    return small ? lg - __logf(p) : lg;
}

__device__ __forceinline__ float hardkuma(float la, float lb) {
    float a = fminf(fmaxf(softplus_f(la), 0.01f), 100.f);
    float b = fminf(fmaxf(softplus_f(lb), 0.01f), 100.f);

    const float lt0 = -2.4849066497880004f;   // ln(1/12)
    const float lt1 = -0.08701137698962981f;  // ln(11/12)

    float u0 = -expm1_neg(a * lt0);           // 1 - t0^a
    float u1 = -expm1_neg(a * lt1);           // 1 - t1^a
    float q0 = __expf(b * __logf(u0));        // 1 - p0
    float p1 = __expf(b * __logf(u1));
    float pc = q0 - p1;
    float p0 = 1.f - q0;

    float g = 1.f + __builtin_amdgcn_rcpf(a);
    float lbeta = fast_lgamma(g) + fast_lgamma(b) - fast_lgamma(g + b);
    float mean = fmaf(1.2f * b, __expf(lbeta), -0.1f);
    mean = fminf(fmaxf(mean, 0.f), 1.f);

    float zo = (p0 > p1) ? 0.f : 1.f;
    return (pc < 0.5f) ? zo : mean;
}

// ---------------------------------------------------------------------------
// Fused score GEMMs + HardKuma epilogue. grid (T/128, T/128, B); f32 output.
// (256,1): full unified VGPR/AGPR budget so accA+accB live in registers.
// ---------------------------------------------------------------------------
__global__ __launch_bounds__(256, 1)
void kuma_attn(const bf16* __restrict__ qa, const bf16* __restrict__ ka,
               const bf16* __restrict__ qb, const bf16* __restrict__ kb,
               const float* __restrict__ dist_emb, float* __restrict__ out) {
    const int bidx = blockIdx.z;
    const int t0 = blockIdx.x * 128;
    const int s0 = blockIdx.y * 128;

    __shared__ short lQa[128 * 40], lKa[128 * 40];
    __shared__ short lQb[128 * 40], lKb[128 * 40];
    __shared__ float sDist[23];

    const int tid = threadIdx.x;
    if (tid < 23) sDist[tid] = dist_emb[tid];

    const int wave = tid >> 6, lane = tid & 63;
    const int wm = (wave >> 1) * 64, wn = (wave & 1) * 64;
    const int quad = lane >> 4, r16 = lane & 15;
    const size_t base = (size_t)bidx * 2048 * 256;

    f32x4 accA[4][4] = {};
    f32x4 accB[4][4] = {};

    for (int kk = 0; kk < 256; kk += 32) {
        for (int i = tid; i < 512; i += 256) {
            int r = i >> 2;
            int c = (i & 3) * 8;
            size_t gq = base + (size_t)(t0 + r) * 256 + kk + c;
            size_t gk = base + (size_t)(s0 + r) * 256 + kk + c;
            *(bf16x8*)&lQa[r * 40 + c] = *(const bf16x8*)(qa + gq);
            *(bf16x8*)&lKa[r * 40 + c] = *(const bf16x8*)(ka + gk);
            *(bf16x8*)&lQb[r * 40 + c] = *(const bf16x8*)(qb + gq);
            *(bf16x8*)&lKb[r * 40 + c] = *(const bf16x8*)(kb + gk);
        }
        __syncthreads();
        bf16x8 aA[4], bA[4], aB[4], bB[4];
#pragma unroll
        for (int f = 0; f < 4; f++) {
            int ar = (wm + f * 16 + r16) * 40 + quad * 8;
            int br = (wn + f * 16 + r16) * 40 + quad * 8;
            aA[f] = *(const bf16x8*)&lQa[ar];
            bA[f] = *(const bf16x8*)&lKa[br];
            aB[f] = *(const bf16x8*)&lQb[ar];
            bB[f] = *(const bf16x8*)&lKb[br];
        }
#pragma unroll
        for (int i = 0; i < 4; i++)
#pragma unroll
            for (int j = 0; j < 4; j++) {
                accA[i][j] = __builtin_amdgcn_mfma_f32_16x16x32_bf16(
                    aA[i], bA[j], accA[i][j], 0, 0, 0);
                accB[i][j] = __builtin_amdgcn_mfma_f32_16x16x32_bf16(
                    aB[i], bB[j], accB[i][j], 0, 0, 0);
            }
        __syncthreads();
    }

#pragma unroll
    for (int i = 0; i < 4; i++) {
#pragma unroll
        for (int j = 0; j < 4; j++) {
            int s = s0 + wn + j * 16 + r16;
#pragma unroll
            for (int r = 0; r < 4; r++) {
                int t = t0 + wm + i * 16 + quad * 4 + r;
                int d = s - t;
                d = d < -11 ? -11 : (d > 11 ? 11 : d);
                float rd = sDist[d + 11];
                float att = hardkuma(accA[i][j][r] + rd, accB[i][j][r] + rd);
                out[((size_t)bidx * 2048 + t) * 2048 + s] = att;
            }
        }
    }
}

// ---------------------------------------------------------------------------
extern "C" void kernel_launch(void* const* d_in, const int* in_sizes, int n_in,
                              void* d_out, int out_size, void* d_ws, size_t ws_size,
                              hipStream_t stream) {
    const float* q    = (const float*)d_in[0];
    const float* k    = (const float*)d_in[1];
    const float* Wa1  = (const float*)d_in[2];
    const float* Wa2  = (const float*)d_in[4];
    const float* Wb1  = (const float*)d_in[6];
    const float* Wb2  = (const float*)d_in[8];
    const float* dist = (const float*)d_in[10];
    float* out = (float*)d_out;

    bf16* wsbf = (bf16*)d_ws;
    bf16* Wa1t = wsbf;                 // 512*256
    bf16* Wa2t = Wa1t + 131072;        // 256*256
    bf16* Wb1t = Wa2t + 65536;
    bf16* Wb2t = Wb1t + 131072;
    bf16* qa   = Wb2t + 65536;         // 8192*256 each
    bf16* ka   = qa + 2097152;
    bf16* qb   = ka + 2097152;
    bf16* kb   = qb + 2097152;
    // total ws ~17.6 MB

    prep_weights<<<1536, 256, 0, stream>>>(Wa1, Wa2, Wb1, Wb2,
                                           Wa1t, Wa2t, Wb1t, Wb2t);

    dim3 g1(128, 1, 2), blk(256, 1, 1);
    mlp_gemm<512, true ><<<g1, blk, 0, stream>>>(q, k, Wa1t, qa, ka);
    mlp_gemm<256, false><<<g1, blk, 0, stream>>>(qa, ka, Wa2t, qa, ka);
    mlp_gemm<512, true ><<<g1, blk, 0, stream>>>(q, k, Wb1t, qb, kb);
    mlp_gemm<256, false><<<g1, blk, 0, stream>>>(qb, kb, Wb2t, qb, kb);

    dim3 g2(16, 16, 4);
    kuma_attn<<<g2, blk, 0, stream>>>(qa, ka, qb, kb, dist, out);
}

// Round 5
// 260.497 us; speedup vs baseline: 3.0364x; 1.6714x over previous
//
#include <hip/hip_runtime.h>
#include <hip/hip_bf16.h>
#include <math.h>

typedef __hip_bfloat16 bf16;
typedef short bf16x8 __attribute__((ext_vector_type(8)));   // 8 bf16 raw (4 VGPRs)
typedef float f32x4 __attribute__((ext_vector_type(4)));

union alignas(16) Pack8 { bf16 h[8]; bf16x8 v; };

// ---------------------------------------------------------------------------
// All four weight transposes f32 -> bf16 in one dispatch.
// ---------------------------------------------------------------------------
__global__ void prep_weights(const float* __restrict__ Wa1, const float* __restrict__ Wa2,
                             const float* __restrict__ Wb1, const float* __restrict__ Wb2,
                             bf16* __restrict__ oa1, bf16* __restrict__ oa2,
                             bf16* __restrict__ ob1, bf16* __restrict__ ob2) {
    int idx = blockIdx.x * 256 + threadIdx.x;   // grid covers 393216
    if (idx < 131072) {
        int n = idx >> 9, k = idx & 511;
        oa1[idx] = __float2bfloat16(Wa1[k * 256 + n]);
    } else if (idx < 196608) {
        int i = idx - 131072; int n = i >> 8, k = i & 255;
        oa2[i] = __float2bfloat16(Wa2[k * 256 + n]);
    } else if (idx < 327680) {
        int i = idx - 196608; int n = i >> 9, k = i & 511;
        ob1[i] = __float2bfloat16(Wb1[k * 256 + n]);
    } else {
        int i = idx - 327680; int n = i >> 8, k = i & 255;
        ob2[i] = __float2bfloat16(Wb2[k * 256 + n]);
    }
}

// ---------------------------------------------------------------------------
// MLP layer GEMM, both branches in one dispatch. grid (128,1,4):
// z selects (X,Y) pair; Wt = (z<2) ? Wta : Wtb.
// Y = relu(X @ W). Block = 64 rows x 256 cols. In-place safe (disjoint rows,
// all reads precede writes).
// ---------------------------------------------------------------------------
template<int KDIM, bool F32IN>
__global__ __launch_bounds__(256)
void mlp_gemm(const void* __restrict__ X0, const void* __restrict__ X1,
              const void* __restrict__ X2, const void* __restrict__ X3,
              const bf16* __restrict__ Wta, const bf16* __restrict__ Wtb,
              bf16* __restrict__ Y0, bf16* __restrict__ Y1,
              bf16* __restrict__ Y2, bf16* __restrict__ Y3) {
    const void* Xs[4] = {X0, X1, X2, X3};
    bf16*       Ys[4] = {Y0, Y1, Y2, Y3};
    const int z = blockIdx.z;
    const void* X = Xs[z];
    bf16* Y = Ys[z];
    const bf16* Wt = (z < 2) ? Wta : Wtb;
    const int m0 = blockIdx.x * 64;

    __shared__ short lA[64 * 40];
    __shared__ short lB[256 * 40];

    const int tid  = threadIdx.x;
    const int wave = tid >> 6, lane = tid & 63;
    const int wn = wave * 64;
    const int quad = lane >> 4, r16 = lane & 15;

    f32x4 acc[4][4] = {};

    for (int kk = 0; kk < KDIM; kk += 32) {
        {
            int r = tid >> 2;
            int c = (tid & 3) * 8;
            if (F32IN) {
                const float* p = (const float*)X + (size_t)(m0 + r) * KDIM + kk + c;
                Pack8 u;
#pragma unroll
                for (int j = 0; j < 8; j++) u.h[j] = __float2bfloat16(p[j]);
                *(bf16x8*)&lA[r * 40 + c] = u.v;
            } else {
                *(bf16x8*)&lA[r * 40 + c] =
                    *(const bf16x8*)((const bf16*)X + (size_t)(m0 + r) * KDIM + kk + c);
            }
        }
        for (int i = tid; i < 1024; i += 256) {
            int r = i >> 2;
            int c = (i & 3) * 8;
            *(bf16x8*)&lB[r * 40 + c] =
                *(const bf16x8*)(Wt + (size_t)r * KDIM + kk + c);
        }
        __syncthreads();
        bf16x8 af[4], bfr[4];
#pragma unroll
        for (int f = 0; f < 4; f++) {
            af[f]  = *(const bf16x8*)&lA[(f * 16 + r16) * 40 + quad * 8];
            bfr[f] = *(const bf16x8*)&lB[(wn + f * 16 + r16) * 40 + quad * 8];
        }
#pragma unroll
        for (int i = 0; i < 4; i++)
#pragma unroll
            for (int j = 0; j < 4; j++)
                acc[i][j] = __builtin_amdgcn_mfma_f32_16x16x32_bf16(
                    af[i], bfr[j], acc[i][j], 0, 0, 0);
        __syncthreads();
    }

#pragma unroll
    for (int i = 0; i < 4; i++) {
        int rbase = m0 + i * 16 + quad * 4;
#pragma unroll
        for (int j = 0; j < 4; j++) {
            int col = wn + j * 16 + r16;
#pragma unroll
            for (int r = 0; r < 4; r++) {
                float v = acc[i][j][r];
                v = v > 0.f ? v : 0.f;
                Y[(size_t)(rbase + r) * 256 + col] = __float2bfloat16(v);
            }
        }
    }
}

// ---------------------------------------------------------------------------
// Fast range-reduced math
// ---------------------------------------------------------------------------
__device__ __forceinline__ float softplus_f(float x) {
    float r = __logf(1.f + __expf(x));
    return x > 15.f ? x : r;
}

__device__ __forceinline__ float expm1_neg(float y) {   // y <= 0
    float p = y * (1.f + y * (0.5f + y * (1.f/6.f + y * (1.f/24.f +
              y * (1.f/120.f + y * (1.f/720.f))))));
    float e = __expf(y) - 1.f;
    return y > -0.28f ? p : e;
}

// Stirling body for z >= 8 (after +8 shift), 2 correction terms
__device__ __forceinline__ float stirling8(float z) {
    float lz = __logf(z);
    float iz = __builtin_amdgcn_rcpf(z);
    return (z - 0.5f) * lz - z + 0.918938533f
         + iz * (0.0833333333f - 0.0027777778f * iz * iz);
}

__device__ __forceinline__ float shift_prod(float x) {  // x(x+1)...(x+7)
    return x * (x + 1.f) * (x + 2.f) * (x + 3.f)
             * (x + 4.f) * (x + 5.f) * (x + 6.f) * (x + 7.f);
}

__device__ __forceinline__ float hardkuma(float la, float lb) {
    float a = fminf(fmaxf(softplus_f(la), 0.01f), 100.f);
    float b = fminf(fmaxf(softplus_f(lb), 0.01f), 100.f);

    const float lt0 = -2.4849066497880004f;   // ln(1/12)
    const float lt1 = -0.08701137698962981f;  // ln(11/12)

    float u0 = -expm1_neg(a * lt0);           // 1 - t0^a
    float u1 = -expm1_neg(a * lt1);           // 1 - t1^a
    float q0 = __expf(b * __logf(u0));        // 1 - p0
    float p1 = __expf(b * __logf(u1));
    float pc = q0 - p1;
    float p0 = 1.f - q0;

    // lbeta = lgamma(g) + lgamma(b) - lgamma(g+b), g = 1 + 1/a.
    // Shift all three by +8; the three shift-product logs fuse into ONE log:
    //   lbeta = st(g+8) + st(b+8) - st(g+b+8) + log( pgb / (pg*pb) )
    float g = 1.f + __builtin_amdgcn_rcpf(a);
    float gb = g + b;
    float pg  = shift_prod(g);
    float pb  = shift_prod(b);
    float pgb = shift_prod(gb);
    float lbeta = stirling8(g + 8.f) + stirling8(b + 8.f) - stirling8(gb + 8.f)
                + __logf(pgb * __builtin_amdgcn_rcpf(pg * pb));
    float mean = fmaf(1.2f * b, __expf(lbeta), -0.1f);
    mean = fminf(fmaxf(mean, 0.f), 1.f);

    float zo = (p0 > p1) ? 0.f : 1.f;
    return (pc < 0.5f) ? zo : mean;
}

// ---------------------------------------------------------------------------
// Fused score GEMMs + HardKuma epilogue. Tile 128(t) x 64(s); 4 waves of
// 64x32; grid (16, 32, 4). (256,2): >=2 blocks/CU for phase overlap.
// ---------------------------------------------------------------------------
__global__ __launch_bounds__(256, 2)
void kuma_attn(const bf16* __restrict__ qa, const bf16* __restrict__ ka,
               const bf16* __restrict__ qb, const bf16* __restrict__ kb,
               const float* __restrict__ dist_emb, float* __restrict__ out) {
    const int bidx = blockIdx.z;
    const int t0 = blockIdx.x * 128;
    const int s0 = blockIdx.y * 64;

    __shared__ short lQa[128 * 40], lQb[128 * 40];
    __shared__ short lKa[64 * 40],  lKb[64 * 40];
    __shared__ float sDist[23];

    const int tid = threadIdx.x;
    if (tid < 23) sDist[tid] = dist_emb[tid];

    const int wave = tid >> 6, lane = tid & 63;
    const int wm = (wave >> 1) * 64, wn = (wave & 1) * 32;
    const int quad = lane >> 4, r16 = lane & 15;
    const size_t base = (size_t)bidx * 2048 * 256;

    f32x4 accA[4][2] = {};
    f32x4 accB[4][2] = {};

    for (int kk = 0; kk < 256; kk += 32) {
        // Q tiles: 512 chunk jobs (2 per thread), both branches
        {
            int r = tid >> 2, c = (tid & 3) * 8;
            size_t gq = base + (size_t)(t0 + r) * 256 + kk + c;
            *(bf16x8*)&lQa[r * 40 + c] = *(const bf16x8*)(qa + gq);
            *(bf16x8*)&lQb[r * 40 + c] = *(const bf16x8*)(qb + gq);
            int i2 = tid + 256;
            int r2 = i2 >> 2, c2 = (i2 & 3) * 8;
            size_t gq2 = base + (size_t)(t0 + r2) * 256 + kk + c2;
            *(bf16x8*)&lQa[r2 * 40 + c2] = *(const bf16x8*)(qa + gq2);
            *(bf16x8*)&lQb[r2 * 40 + c2] = *(const bf16x8*)(qb + gq2);
            // K tiles: 256 chunk jobs (1 per thread)
            size_t gk = base + (size_t)(s0 + (tid >> 2)) * 256 + kk + c;
            *(bf16x8*)&lKa[r * 40 + c] = *(const bf16x8*)(ka + gk);
            *(bf16x8*)&lKb[r * 40 + c] = *(const bf16x8*)(kb + gk);
        }
        __syncthreads();
        bf16x8 aA[4], aB[4], bA[2], bB[2];
#pragma unroll
        for (int f = 0; f < 4; f++) {
            int ar = (wm + f * 16 + r16) * 40 + quad * 8;
            aA[f] = *(const bf16x8*)&lQa[ar];
            aB[f] = *(const bf16x8*)&lQb[ar];
        }
#pragma unroll
        for (int f = 0; f < 2; f++) {
            int br = (wn + f * 16 + r16) * 40 + quad * 8;
            bA[f] = *(const bf16x8*)&lKa[br];
            bB[f] = *(const bf16x8*)&lKb[br];
        }
#pragma unroll
        for (int i = 0; i < 4; i++)
#pragma unroll
            for (int j = 0; j < 2; j++) {
                accA[i][j] = __builtin_amdgcn_mfma_f32_16x16x32_bf16(
                    aA[i], bA[j], accA[i][j], 0, 0, 0);
                accB[i][j] = __builtin_amdgcn_mfma_f32_16x16x32_bf16(
                    aB[i], bB[j], accB[i][j], 0, 0, 0);
            }
        __syncthreads();
    }

#pragma unroll
    for (int i = 0; i < 4; i++) {
#pragma unroll
        for (int j = 0; j < 2; j++) {
            int s = s0 + wn + j * 16 + r16;
#pragma unroll
            for (int r = 0; r < 4; r++) {
                int t = t0 + wm + i * 16 + quad * 4 + r;
                int d = s - t;
                d = d < -11 ? -11 : (d > 11 ? 11 : d);
                float rd = sDist[d + 11];
                float att = hardkuma(accA[i][j][r] + rd, accB[i][j][r] + rd);
                out[((size_t)bidx * 2048 + t) * 2048 + s] = att;
            }
        }
    }
}

// ---------------------------------------------------------------------------
extern "C" void kernel_launch(void* const* d_in, const int* in_sizes, int n_in,
                              void* d_out, int out_size, void* d_ws, size_t ws_size,
                              hipStream_t stream) {
    const float* q    = (const float*)d_in[0];
    const float* k    = (const float*)d_in[1];
    const float* Wa1  = (const float*)d_in[2];
    const float* Wa2  = (const float*)d_in[4];
    const float* Wb1  = (const float*)d_in[6];
    const float* Wb2  = (const float*)d_in[8];
    const float* dist = (const float*)d_in[10];
    float* out = (float*)d_out;

    bf16* wsbf = (bf16*)d_ws;
    bf16* Wa1t = wsbf;                 // 512*256
    bf16* Wa2t = Wa1t + 131072;        // 256*256
    bf16* Wb1t = Wa2t + 65536;
    bf16* Wb2t = Wb1t + 131072;
    bf16* qa   = Wb2t + 65536;         // 8192*256 each
    bf16* ka   = qa + 2097152;
    bf16* qb   = ka + 2097152;
    bf16* kb   = qb + 2097152;
    // total ws ~17.6 MB

    prep_weights<<<1536, 256, 0, stream>>>(Wa1, Wa2, Wb1, Wb2,
                                           Wa1t, Wa2t, Wb1t, Wb2t);

    dim3 g1(128, 1, 4), blk(256, 1, 1);
    // layer 1: z = {q@Wa1, k@Wa1, q@Wb1, k@Wb1}
    mlp_gemm<512, true ><<<g1, blk, 0, stream>>>(q, k, q, k, Wa1t, Wb1t,
                                                 qa, ka, qb, kb);
    // layer 2 (in-place): z = {qa@Wa2, ka@Wa2, qb@Wb2, kb@Wb2}
    mlp_gemm<256, false><<<g1, blk, 0, stream>>>(qa, ka, qb, kb, Wa2t, Wb2t,
                                                 qa, ka, qb, kb);

    dim3 g2(16, 32, 4);
    kuma_attn<<<g2, blk, 0, stream>>>(qa, ka, qb, kb, dist, out);
}

// Round 7
// 207.114 us; speedup vs baseline: 3.8190x; 1.2578x over previous
//
#include <hip/hip_runtime.h>
#include <hip/hip_bf16.h>
#include <math.h>

typedef __hip_bfloat16 bf16;
typedef short bf16x8 __attribute__((ext_vector_type(8)));   // 8 bf16 raw (4 VGPRs)
typedef float f32x4 __attribute__((ext_vector_type(4)));

union alignas(16) Pack8 { bf16 h[8]; bf16x8 v; };

// native base-2 transcendentals (v_exp_f32 / v_log_f32)
#define EXP2F(x) __builtin_amdgcn_exp2f(x)
#define LOG2F(x) __builtin_amdgcn_logf(x)
#define RCPF(x)  __builtin_amdgcn_rcpf(x)

// ---------------------------------------------------------------------------
// All four weight transposes f32 -> bf16 in one dispatch.
// ---------------------------------------------------------------------------
__global__ void prep_weights(const float* __restrict__ Wa1, const float* __restrict__ Wa2,
                             const float* __restrict__ Wb1, const float* __restrict__ Wb2,
                             bf16* __restrict__ oa1, bf16* __restrict__ oa2,
                             bf16* __restrict__ ob1, bf16* __restrict__ ob2) {
    int idx = blockIdx.x * 256 + threadIdx.x;   // grid covers 393216
    if (idx < 131072) {
        int n = idx >> 9, k = idx & 511;
        oa1[idx] = __float2bfloat16(Wa1[k * 256 + n]);
    } else if (idx < 196608) {
        int i = idx - 131072; int n = i >> 8, k = i & 255;
        oa2[i] = __float2bfloat16(Wa2[k * 256 + n]);
    } else if (idx < 327680) {
        int i = idx - 196608; int n = i >> 9, k = i & 511;
        ob1[i] = __float2bfloat16(Wb1[k * 256 + n]);
    } else {
        int i = idx - 327680; int n = i >> 8, k = i & 255;
        ob2[i] = __float2bfloat16(Wb2[k * 256 + n]);
    }
}

// ---------------------------------------------------------------------------
// Fused 2-layer MLP: Y = relu(relu(X @ W1) @ W2). One block = 64 rows through
// BOTH layers; h lives in LDS (never hits global). grid (128,1,4):
// z = {q@a, k@a, q@b, k@b}. LDS 59.4 KB -> 2 blocks/CU.
// ---------------------------------------------------------------------------
__global__ __launch_bounds__(256, 2)
void mlp_fused(const float* __restrict__ q, const float* __restrict__ k,
               const bf16* __restrict__ Wa1t, const bf16* __restrict__ Wa2t,
               const bf16* __restrict__ Wb1t, const bf16* __restrict__ Wb2t,
               bf16* __restrict__ qa, bf16* __restrict__ ka,
               bf16* __restrict__ qb, bf16* __restrict__ kb) {
    const int z = blockIdx.z;
    const float* X  = (z & 1) ? k : q;
    const bf16*  W1 = (z >> 1) ? Wb1t : Wa1t;
    const bf16*  W2 = (z >> 1) ? Wb2t : Wa2t;
    bf16* Y = (z == 0) ? qa : (z == 1) ? ka : (z == 2) ? qb : kb;
    const int m0 = blockIdx.x * 64;

    __shared__ short lA[64 * 40];     // layer-1 A tile
    __shared__ short lB[256 * 40];    // W staging (both layers)
    __shared__ short lH[64 * 264];    // h: 64 rows x 256 cols (+8 pad)

    const int tid  = threadIdx.x;
    const int wave = tid >> 6, lane = tid & 63;
    const int wn = wave * 64;
    const int quad = lane >> 4, r16 = lane & 15;

    // ---- layer 1: K = 512, X is f32 (convert during staging)
    {
        f32x4 acc[4][4] = {};
        for (int kk = 0; kk < 512; kk += 32) {
            {
                int r = tid >> 2, c = (tid & 3) * 8;
                const float* p = X + (size_t)(m0 + r) * 512 + kk + c;
                Pack8 u;
#pragma unroll
                for (int j = 0; j < 8; j++) u.h[j] = __float2bfloat16(p[j]);
                *(bf16x8*)&lA[r * 40 + c] = u.v;
            }
            for (int i = tid; i < 1024; i += 256) {
                int r = i >> 2, c = (i & 3) * 8;
                *(bf16x8*)&lB[r * 40 + c] =
                    *(const bf16x8*)(W1 + (size_t)r * 512 + kk + c);
            }
            __syncthreads();
            bf16x8 af[4], bfr[4];
#pragma unroll
            for (int f = 0; f < 4; f++) {
                af[f]  = *(const bf16x8*)&lA[(f * 16 + r16) * 40 + quad * 8];
                bfr[f] = *(const bf16x8*)&lB[(wn + f * 16 + r16) * 40 + quad * 8];
            }
#pragma unroll
            for (int i = 0; i < 4; i++)
#pragma unroll
                for (int j = 0; j < 4; j++)
                    acc[i][j] = __builtin_amdgcn_mfma_f32_16x16x32_bf16(
                        af[i], bfr[j], acc[i][j], 0, 0, 0);
            __syncthreads();
        }
        // h -> LDS (relu, bf16); local row = i*16+quad*4+r, col = wn+j*16+r16
#pragma unroll
        for (int i = 0; i < 4; i++)
#pragma unroll
            for (int j = 0; j < 4; j++)
#pragma unroll
                for (int r = 0; r < 4; r++) {
                    float v = acc[i][j][r];
                    v = v > 0.f ? v : 0.f;
                    ((bf16*)lH)[(i * 16 + quad * 4 + r) * 264 + wn + j * 16 + r16] =
                        __float2bfloat16(v);
                }
    }
    __syncthreads();

    // ---- layer 2: K = 256, A comes from lH
    f32x4 acc2[4][4] = {};
    for (int kk = 0; kk < 256; kk += 32) {
        for (int i = tid; i < 1024; i += 256) {
            int r = i >> 2, c = (i & 3) * 8;
            *(bf16x8*)&lB[r * 40 + c] =
                *(const bf16x8*)(W2 + (size_t)r * 256 + kk + c);
        }
        __syncthreads();
        bf16x8 af[4], bfr[4];
#pragma unroll
        for (int f = 0; f < 4; f++) {
            af[f]  = *(const bf16x8*)&lH[(f * 16 + r16) * 264 + kk + quad * 8];
            bfr[f] = *(const bf16x8*)&lB[(wn + f * 16 + r16) * 40 + quad * 8];
        }
#pragma unroll
        for (int i = 0; i < 4; i++)
#pragma unroll
            for (int j = 0; j < 4; j++)
                acc2[i][j] = __builtin_amdgcn_mfma_f32_16x16x32_bf16(
                    af[i], bfr[j], acc2[i][j], 0, 0, 0);
        __syncthreads();
    }

#pragma unroll
    for (int i = 0; i < 4; i++) {
        int rbase = m0 + i * 16 + quad * 4;
#pragma unroll
        for (int j = 0; j < 4; j++) {
            int col = wn + j * 16 + r16;
#pragma unroll
            for (int r = 0; r < 4; r++) {
                float v = acc2[i][j][r];
                v = v > 0.f ? v : 0.f;
                Y[(size_t)(rbase + r) * 256 + col] = __float2bfloat16(v);
            }
        }
    }
}

// ---------------------------------------------------------------------------
// Fast math in native log2/exp2 units
// ---------------------------------------------------------------------------
__device__ __forceinline__ float softplus2(float x) {
    // ln(1+e^x) = ln2 * log2(1 + 2^(x*log2e)); overflow -> inf -> clamped later
    return 0.69314718f * LOG2F(1.f + EXP2F(1.44269504f * x));
}

// log2(Gamma(z)) for z >= 4 (Stirling, 2 corrections, natural->log2 folded)
__device__ __forceinline__ float stirl2(float z) {
    float iz = RCPF(z);
    return (z - 0.5f) * LOG2F(z) - 1.44269504f * z + 1.32574806f
         + iz * (0.12022651f - 0.00400749f * iz * iz);
}

__device__ __forceinline__ float sp4(float x) {   // x(x+1)(x+2)(x+3)
    return (x * (x + 1.f)) * ((x + 2.f) * (x + 3.f));
}

__device__ __forceinline__ float hardkuma(float la, float lb) {
    float a = fminf(fmaxf(softplus2(la), 0.01f), 100.f);
    float b = fminf(fmaxf(softplus2(lb), 0.01f), 100.f);

    const float c0 = -3.58496250f;    // log2(1/12)
    const float c1 = -0.12553088f;    // log2(11/12)

    float u0 = 1.f - EXP2F(a * c0);           // 1 - t0^a
    float u1 = 1.f - EXP2F(a * c1);           // 1 - t1^a
    float q0 = EXP2F(b * LOG2F(u0));          // 1 - p0
    float p1 = EXP2F(b * LOG2F(u1));          // P(h=1)
    float pc = q0 - p1;
    float p0 = 1.f - q0;

    // lbeta (log2 units): lgammas shifted +4 into Stirling domain; the three
    // shift-product logs fuse into ONE log2.
    float g  = 1.f + RCPF(a);
    float gb = g + b;
    float lb2 = stirl2(g + 4.f) + stirl2(b + 4.f) - stirl2(gb + 4.f)
              + LOG2F(sp4(gb) * RCPF(sp4(g) * sp4(b)));
    float mean = fmaf(1.2f * b, EXP2F(lb2), -0.1f);
    mean = fminf(fmaxf(mean, 0.f), 1.f);

    float zo = (p0 > p1) ? 0.f : 1.f;
    return (pc < 0.5f) ? zo : mean;
}

// ---------------------------------------------------------------------------
// Fused score GEMMs + HardKuma epilogue. Tile 128(t) x 64(s); 4 waves of
// 64x32; grid (16, 32, 4).
// ---------------------------------------------------------------------------
__global__ __launch_bounds__(256, 2)
void kuma_attn(const bf16* __restrict__ qa, const bf16* __restrict__ ka,
               const bf16* __restrict__ qb, const bf16* __restrict__ kb,
               const float* __restrict__ dist_emb, float* __restrict__ out) {
    const int bidx = blockIdx.z;
    const int t0 = blockIdx.x * 128;
    const int s0 = blockIdx.y * 64;

    __shared__ short lQa[128 * 40], lQb[128 * 40];
    __shared__ short lKa[64 * 40],  lKb[64 * 40];
    __shared__ float sDist[23];

    const int tid = threadIdx.x;
    if (tid < 23) sDist[tid] = dist_emb[tid];

    const int wave = tid >> 6, lane = tid & 63;
    const int wm = (wave >> 1) * 64, wn = (wave & 1) * 32;
    const int quad = lane >> 4, r16 = lane & 15;
    const size_t base = (size_t)bidx * 2048 * 256;

    f32x4 accA[4][2] = {};
    f32x4 accB[4][2] = {};

    for (int kk = 0; kk < 256; kk += 32) {
        {
            int r = tid >> 2, c = (tid & 3) * 8;
            size_t gq = base + (size_t)(t0 + r) * 256 + kk + c;
            *(bf16x8*)&lQa[r * 40 + c] = *(const bf16x8*)(qa + gq);
            *(bf16x8*)&lQb[r * 40 + c] = *(const bf16x8*)(qb + gq);
            int i2 = tid + 256;
            int r2 = i2 >> 2, c2 = (i2 & 3) * 8;
            size_t gq2 = base + (size_t)(t0 + r2) * 256 + kk + c2;
            *(bf16x8*)&lQa[r2 * 40 + c2] = *(const bf16x8*)(qa + gq2);
            *(bf16x8*)&lQb[r2 * 40 + c2] = *(const bf16x8*)(qb + gq2);
            size_t gk = base + (size_t)(s0 + r) * 256 + kk + c;
            *(bf16x8*)&lKa[r * 40 + c] = *(const bf16x8*)(ka + gk);
            *(bf16x8*)&lKb[r * 40 + c] = *(const bf16x8*)(kb + gk);
        }
        __syncthreads();
        bf16x8 aA[4], aB[4], bA[2], bB[2];
#pragma unroll
        for (int f = 0; f < 4; f++) {
            int ar = (wm + f * 16 + r16) * 40 + quad * 8;
            aA[f] = *(const bf16x8*)&lQa[ar];
            aB[f] = *(const bf16x8*)&lQb[ar];
        }
#pragma unroll
        for (int f = 0; f < 2; f++) {
            int br = (wn + f * 16 + r16) * 40 + quad * 8;
            bA[f] = *(const bf16x8*)&lKa[br];
            bB[f] = *(const bf16x8*)&lKb[br];
        }
#pragma unroll
        for (int i = 0; i < 4; i++)
#pragma unroll
            for (int j = 0; j < 2; j++) {
                accA[i][j] = __builtin_amdgcn_mfma_f32_16x16x32_bf16(
                    aA[i], bA[j], accA[i][j], 0, 0, 0);
                accB[i][j] = __builtin_amdgcn_mfma_f32_16x16x32_bf16(
                    aB[i], bB[j], accB[i][j], 0, 0, 0);
            }
        __syncthreads();
    }

#pragma unroll
    for (int i = 0; i < 4; i++) {
#pragma unroll
        for (int j = 0; j < 2; j++) {
            int s = s0 + wn + j * 16 + r16;
#pragma unroll
            for (int r = 0; r < 4; r++) {
                int t = t0 + wm + i * 16 + quad * 4 + r;
                int d = s - t;
                d = d < -11 ? -11 : (d > 11 ? 11 : d);
                float rd = sDist[d + 11];
                float att = hardkuma(accA[i][j][r] + rd, accB[i][j][r] + rd);
                out[((size_t)bidx * 2048 + t) * 2048 + s] = att;
            }
        }
    }
}

// ---------------------------------------------------------------------------
extern "C" void kernel_launch(void* const* d_in, const int* in_sizes, int n_in,
                              void* d_out, int out_size, void* d_ws, size_t ws_size,
                              hipStream_t stream) {
    const float* q    = (const float*)d_in[0];
    const float* k    = (const float*)d_in[1];
    const float* Wa1  = (const float*)d_in[2];
    const float* Wa2  = (const float*)d_in[4];
    const float* Wb1  = (const float*)d_in[6];
    const float* Wb2  = (const float*)d_in[8];
    const float* dist = (const float*)d_in[10];
    float* out = (float*)d_out;

    bf16* wsbf = (bf16*)d_ws;
    bf16* Wa1t = wsbf;                 // 512*256
    bf16* Wa2t = Wa1t + 131072;        // 256*256
    bf16* Wb1t = Wa2t + 65536;
    bf16* Wb2t = Wb1t + 131072;
    bf16* qa   = Wb2t + 65536;         // 8192*256 each
    bf16* ka   = qa + 2097152;
    bf16* qb   = ka + 2097152;
    bf16* kb   = qb + 2097152;
    // total ws ~17.6 MB

    prep_weights<<<1536, 256, 0, stream>>>(Wa1, Wa2, Wb1, Wb2,
                                           Wa1t, Wa2t, Wb1t, Wb2t);

    dim3 g1(128, 1, 4), blk(256, 1, 1);
    mlp_fused<<<g1, blk, 0, stream>>>(q, k, Wa1t, Wa2t, Wb1t, Wb2t,
                                      qa, ka, qb, kb);

    dim3 g2(16, 32, 4);
    kuma_attn<<<g2, blk, 0, stream>>>(qa, ka, qb, kb, dist, out);
}